// Round 5
// baseline (279.703 us; speedup 1.0000x reference)
//
#include <hip/hip_runtime.h>
#include <cstdint>

typedef unsigned short u16;
typedef __bf16 bf16x8 __attribute__((ext_vector_type(8)));
typedef float f32x4 __attribute__((ext_vector_type(4)));
typedef short s4 __attribute__((ext_vector_type(4)));

#define T_SEQ 2048
#define NH 16

// RTNE float -> bf16 bits
__device__ __forceinline__ u16 f2bf(float f) {
  union { float f; uint32_t u; } x; x.f = f;
  uint32_t r = (x.u + 0x7fffu + ((x.u >> 16) & 1u)) >> 16;
  return (u16)r;
}

// pack two floats -> two bf16 (RTNE)
__device__ __forceinline__ uint32_t pk2bf(float a, float b) {
  union { float f; uint32_t u; } x, y; x.f = a; y.f = b;
  uint32_t lo = (x.u + 0x7fffu + ((x.u >> 16) & 1u)) >> 16;
  uint32_t hi = (y.u + 0x7fffu + ((y.u >> 16) & 1u)) >> 16;
  return lo | (hi << 16);
}

// 8 fp32 -> 8 bf16 (one uint4 store)
__device__ __forceinline__ void cvt8(u16* dst, const float* src) {
  float4 a = *(const float4*)src;
  float4 b = *(const float4*)(src + 4);
  uint4 o;
  o.x = pk2bf(a.x, a.y); o.y = pk2bf(a.z, a.w);
  o.z = pk2bf(b.x, b.y); o.w = pk2bf(b.z, b.w);
  *(uint4*)dst = o;
}

// fused fp32 -> bf16 conversion of x, w_qkv, w_o (dst regions contiguous in ws)
__global__ __launch_bounds__(256) void cvt_all(const float* __restrict__ x,
                                               const float* __restrict__ wq,
                                               const float* __restrict__ wo,
                                               u16* __restrict__ dst) {
  int i = blockIdx.x * 256 + threadIdx.x;
  const float* src; int off;
  if (i < 524288)      { src = x;  off = 0; }
  else if (i < 917504) { src = wq; off = 524288; }
  else                 { src = wo; off = 917504; }
  cvt8(&dst[(size_t)i * 8], &src[(size_t)(i - off) * 8]);
}

// f32x4 accumulator quad -> 4 bf16
__device__ __forceinline__ s4 cvt4(f32x4 v) {
  union { __bf16 b[4]; s4 s; } u;
  u.b[0] = (__bf16)v[0]; u.b[1] = (__bf16)v[1];
  u.b[2] = (__bf16)v[2]; u.b[3] = (__bf16)v[3];
  return u.s;
}

__device__ __forceinline__ f32x4 mfma16(s4 a, s4 b, f32x4 c) {
#if __has_builtin(__builtin_amdgcn_mfma_f32_16x16x16bf16_1k)
  return __builtin_amdgcn_mfma_f32_16x16x16bf16_1k(a, b, c, 0, 0, 0);
#else
  asm("v_mfma_f32_16x16x16_bf16 %0, %1, %2, %0" : "+v"(c) : "v"(a), "v"(b));
  return c;
#endif
}

// native 2^x
__device__ __forceinline__ float exp2fast(float x) {
#if __has_builtin(__builtin_amdgcn_exp2f)
  return __builtin_amdgcn_exp2f(x);
#else
  float r; asm("v_exp_f32 %0, %1" : "=v"(r) : "v"(x)); return r;
#endif
}

// async 16B global -> LDS (HW scatters lane i at ldsbase + i*16)
__device__ __forceinline__ void gl_lds(const u16* g, u16* ldsbase) {
  __builtin_amdgcn_global_load_lds(
      (const __attribute__((address_space(1))) void*)g,
      (__attribute__((address_space(3))) void*)ldsbase, 16, 0, 0);
}

// C[M,N] = A[M,K] * W[N,K]^T. A,W bf16; C fp32 (CF32) or bf16 ws.
// KV: k cols (1024..2047) -> qkv bf16 + outk fp32; v cols (>=2048) ->
//     outv fp32 + TRANSPOSED bf16 into vt (fused transpose_v).
// tile 128x128, BK=64, global_load_lds staging, XOR-swizzled linear LDS,
// bijective XCD-aware block swizzle (grid %8 == 0).
template <bool CF32, bool KV, int WAVES>
__global__ __launch_bounds__(WAVES * 64) void gemm_bt(
    const u16* __restrict__ A, const u16* __restrict__ W,
    void* __restrict__ Cp, float* __restrict__ outk, float* __restrict__ outv,
    u16* __restrict__ vtp, int M, int N, int K) {
  constexpr int NJ = (WAVES == 4) ? 4 : 2;   // N-frags per wave
  constexpr int SI = 16 / WAVES;             // staging iters (8-row groups)
  __shared__ __align__(16) u16 As[128 * 64];
  __shared__ __align__(16) u16 Bs[128 * 64];
  const int tid  = threadIdx.x;
  const int bid  = blockIdx.y * gridDim.x + blockIdx.x;
  const int per  = (gridDim.x * gridDim.y) >> 3;
  const int swz  = (bid & 7) * per + (bid >> 3);
  const int n0   = (swz % gridDim.x) * 128;
  const int m0   = (swz / gridDim.x) * 128;
  const int lane = tid & 63;
  const int wave = tid >> 6;
  const int wm   = (WAVES == 4 ? (wave >> 1) : (wave >> 2)) * 64;
  const int wn   = (WAVES == 4 ? (wave & 1) * 64 : (wave & 3) * 32);
  const int l15  = lane & 15;
  const int quad = lane >> 4;
  const int srow = lane >> 3;   // row within 8-row stage group
  const int sc   = lane & 7;    // 16B chunk within row

  f32x4 acc[4][NJ];
#pragma unroll
  for (int i = 0; i < 4; i++)
#pragma unroll
    for (int j = 0; j < NJ; j++) acc[i][j] = (f32x4){0.f, 0.f, 0.f, 0.f};

  for (int k0 = 0; k0 < K; k0 += 64) {
    __syncthreads();
#pragma unroll
    for (int i = 0; i < SI; i++) {
      int r0  = (i * WAVES + wave) * 8;
      int row = r0 + srow;
      int gc  = (sc ^ (row & 7)) << 3;  // pre-swizzled source column (u16)
      gl_lds(&A[(size_t)(m0 + row) * K + k0 + gc], &As[r0 * 64]);
      gl_lds(&W[(size_t)(n0 + row) * K + k0 + gc], &Bs[r0 * 64]);
    }
    __syncthreads();
#pragma unroll
    for (int kk = 0; kk < 64; kk += 32) {
      bf16x8 af[4], bfr[NJ];
#pragma unroll
      for (int i = 0; i < 4; i++) {
        int arow = wm + i * 16 + l15;
        af[i] = *(const bf16x8*)((const char*)As + arow * 128 +
                                 ((((kk >> 3) + quad) ^ (arow & 7)) << 4));
      }
#pragma unroll
      for (int j = 0; j < NJ; j++) {
        int brow = wn + j * 16 + l15;
        bfr[j] = *(const bf16x8*)((const char*)Bs + brow * 128 +
                                  ((((kk >> 3) + quad) ^ (brow & 7)) << 4));
      }
#pragma unroll
      for (int i = 0; i < 4; i++)
#pragma unroll
        for (int j = 0; j < NJ; j++)
          acc[i][j] = __builtin_amdgcn_mfma_f32_16x16x32_bf16(af[i], bfr[j], acc[i][j], 0, 0, 0);
    }
  }
#pragma unroll
  for (int i = 0; i < 4; i++)
#pragma unroll
    for (int j = 0; j < NJ; j++) {
      const int row0 = m0 + wm + i * 16 + quad * 4;  // 4 consecutive rows
      const int col  = n0 + wn + j * 16 + l15;
      if constexpr (CF32) {
#pragma unroll
        for (int r = 0; r < 4; r++)
          ((float*)Cp)[(size_t)(row0 + r) * N + col] = acc[i][j][r];
      } else if (KV && col >= 2048) {
        // v: fp32 output + transposed bf16 into vt (4 consecutive t -> 8B)
        const int hd = col - 2048;
        const int b_ = row0 >> 11, t_ = row0 & 2047;
        uint2 pk;
        pk.x = pk2bf(acc[i][j][0], acc[i][j][1]);
        pk.y = pk2bf(acc[i][j][2], acc[i][j][3]);
        *(uint2*)&vtp[((size_t)(b_ * NH + (hd >> 6)) * 64 + (hd & 63)) * 2048 + t_] = pk;
#pragma unroll
        for (int r = 0; r < 4; r++)
          outv[(size_t)(row0 + r) * 1024 + hd] = acc[i][j][r];
      } else {
#pragma unroll
        for (int r = 0; r < 4; r++) {
          float v = acc[i][j][r];
          ((u16*)Cp)[(size_t)(row0 + r) * N + col] = f2bf(v);
          if constexpr (KV) {
            if (col >= 1024) outk[(size_t)(row0 + r) * 1024 + (col - 1024)] = v;
          }
        }
      }
    }
}

// Flash-style causal attention, swapped QK^T (S^T = mfma(K,Q)), paired q-tiles
// (pair, 31-pair) -> 33 uniform steps/block.
// K: 3-buffer LDS pipeline, counted vmcnt (stage s+2 in flight across barriers).
// V: NO LDS — 16x global_load_dwordx2 into registers right after the barrier;
//    QK^T + softmax hides the (L2-resident) latency.  This removes ~45% of the
//    LDS-pipe traffic that saturated the CU's DS pipe (round-4 diagnosis).
// Softmax in log2 domain with defer-max (THR=8).  setprio around MFMA clusters.
__global__ __launch_bounds__(256) void attn(const u16* __restrict__ qkv,
                                            const u16* __restrict__ vt,
                                            u16* __restrict__ o) {
  __shared__ __align__(16) u16 Ks[3][64 * 64];

  const int tid  = threadIdx.x;
  const int pair = blockIdx.x;          // q-tiles (pair, 31-pair)
  const int bh   = blockIdx.y;
  const int b    = bh >> 4, h = bh & 15;
  const int lane = tid & 63, wave = tid >> 6;
  const int l15  = lane & 15, quad = lane >> 4;
  const int srow = lane >> 3, sc = lane & 7;
  const size_t qbase = (size_t)b * T_SEQ * 3072;
  const size_t vbase = (size_t)(b * NH + h) * 64 * 2048;
  const float C = 0.1803368801f;        // 0.125 * log2(e)

  const int qtA = pair, qtB = 31 - pair;
  const int wq0A = qtA * 64 + wave * 16;
  const int wq0B = qtB * 64 + wave * 16;
  const u16* qpA = &qkv[qbase + (size_t)(wq0A + l15) * 3072 + h * 64];
  const u16* qpB = &qkv[qbase + (size_t)(wq0B + l15) * 3072 + h * 64];
  bf16x8 qf0 = *(const bf16x8*)&qpA[quad * 8];
  bf16x8 qf1 = *(const bf16x8*)&qpA[32 + quad * 8];
  const bf16x8 qB0 = *(const bf16x8*)&qpB[quad * 8];
  const bf16x8 qB1 = *(const bf16x8*)&qpB[32 + quad * 8];

  // V^T row base pointers: vp[n] -> V^T[d = n*16+l15][quad*4 + ...]
  const u16* vp[4];
#pragma unroll
  for (int n = 0; n < 4; n++)
    vp[n] = &vt[vbase + (size_t)(n * 16 + l15) * 2048 + quad * 4];

  int qt = qtA, wq0 = wq0A, qrow = wq0A + l15;

  f32x4 acc_o[4];
#pragma unroll
  for (int n = 0; n < 4; n++) acc_o[n] = (f32x4){0.f, 0.f, 0.f, 0.f};
  float m2run = -1e30f, lrun = 0.f;

  // step -> k-tile (tile A steps 0..pair, tile B steps pair+1..32)
  auto ktof = [&](int s) { return (s > pair) ? (s - pair - 1) : s; };

  // async stage of step s's K-tile into buffer buf: 2 gl_lds per wave
  auto stage = [&](int buf, int s) {
    const int k0 = ktof(s) * 64;
#pragma unroll
    for (int i = 0; i < 2; i++) {
      int r0  = (wave * 2 + i) * 8;
      int row = r0 + srow;
      int gc  = (sc ^ (row & 7)) << 3;
      gl_lds(&qkv[qbase + (size_t)(k0 + row) * 3072 + 1024 + h * 64 + gc], &Ks[buf][r0 * 64]);
    }
  };

  auto writeout = [&]() {
    float linv = 1.0f / lrun;
#pragma unroll
    for (int r = 0; r < 4; r++) {
      float lr = __shfl(linv, quad * 4 + r);
      int row = wq0 + quad * 4 + r;
#pragma unroll
      for (int n = 0; n < 4; n++)
        o[(size_t)(b * T_SEQ + row) * 1024 + h * 64 + n * 16 + l15] =
            f2bf(acc_o[n][r] * lr);
    }
  };

  stage(0, 0);
  stage(1, 1);
  // retire Q loads + stage(0) (stage(1)'s 2 stay in flight)
  asm volatile("s_waitcnt vmcnt(2)" ::: "memory");

  const int steps = 33;
  for (int s = 0; s < steps; s++) {
    __builtin_amdgcn_s_barrier();         // Ks[s%3] landed in all waves
    __builtin_amdgcn_sched_barrier(0);

    const int kt = ktof(s);
    const int k0 = kt * 64;

    // V-frags for this step: global -> regs (L2-resident vt; QK hides latency)
    s4 vreg[4][4];
#pragma unroll
    for (int j = 0; j < 4; j++)
#pragma unroll
      for (int n = 0; n < 4; n++)
        vreg[j][n] = *(const s4*)(vp[n] + k0 + j * 16);

    if (s + 2 < steps) stage((s + 2) % 3, s + 2);  // overwrites buf[(s-1)%3]

    if (s == pair + 1) {  // q-tile switch: flush tile A, reset, swap Q frags
      writeout();
#pragma unroll
      for (int n = 0; n < 4; n++) acc_o[n] = (f32x4){0.f, 0.f, 0.f, 0.f};
      m2run = -1e30f; lrun = 0.f;
      qt = qtB; wq0 = wq0B; qrow = wq0B + l15;
      qf0 = qB0; qf1 = qB1;
    }

    const int cur = s % 3;

    // S^T[j]: row (quad*4+r) = k_local, col l15 = q  (swizzled Ks reads)
    f32x4 sacc[4];
#pragma unroll
    for (int j = 0; j < 4; j++) sacc[j] = (f32x4){0.f, 0.f, 0.f, 0.f};
    __builtin_amdgcn_s_setprio(1);
#pragma unroll
    for (int j = 0; j < 4; j++) {
      int krow = j * 16 + l15;
      const char* kb = (const char*)&Ks[cur][0] + krow * 128;
      bf16x8 kfa = *(const bf16x8*)(kb + ((quad ^ (krow & 7)) << 4));
      bf16x8 kfb = *(const bf16x8*)(kb + (((4 + quad) ^ (krow & 7)) << 4));
      sacc[j] = __builtin_amdgcn_mfma_f32_16x16x32_bf16(kfa, qf0, sacc[j], 0, 0, 0);
      sacc[j] = __builtin_amdgcn_mfma_f32_16x16x32_bf16(kfb, qf1, sacc[j], 0, 0, 0);
    }
    __builtin_amdgcn_s_setprio(0);

    if (kt == qt) {  // diagonal tile: causal mask on raw scores
#pragma unroll
      for (int j = 0; j < 4; j++)
#pragma unroll
        for (int r = 0; r < 4; r++) {
          int k = k0 + j * 16 + quad * 4 + r;
          if (k > qrow) sacc[j][r] = -1e30f;
        }
    }

    // row max, tree-shaped
    float mj[4];
#pragma unroll
    for (int j = 0; j < 4; j++)
      mj[j] = fmaxf(fmaxf(sacc[j][0], sacc[j][1]), fmaxf(sacc[j][2], sacc[j][3]));
    float mx = fmaxf(fmaxf(mj[0], mj[1]), fmaxf(mj[2], mj[3]));
    mx = fmaxf(mx, __shfl_xor(mx, 16));
    mx = fmaxf(mx, __shfl_xor(mx, 32));
    const float m2x = mx * C;

    // defer-max: only rescale when the max grew by > 8 (log2 domain)
    if (!__all(m2x <= m2run + 8.0f)) {
      const float m2new = fmaxf(m2run, m2x);
      const float alpha = exp2fast(m2run - m2new);
      lrun *= alpha;
      m2run = m2new;
#pragma unroll
      for (int r = 0; r < 4; r++) {
        float ar = __shfl(alpha, quad * 4 + r);
#pragma unroll
        for (int n = 0; n < 4; n++) acc_o[n][r] *= ar;
      }
    }

    // p = exp2(s*C - m2run); tree sum
    const float nm = m2run;
    float ts[4];
#pragma unroll
    for (int j = 0; j < 4; j++) {
#pragma unroll
      for (int r = 0; r < 4; r++) sacc[j][r] = exp2fast(fmaf(sacc[j][r], C, -nm));
      ts[j] = (sacc[j][0] + sacc[j][1]) + (sacc[j][2] + sacc[j][3]);
    }
    float sum = (ts[0] + ts[1]) + (ts[2] + ts[3]);
    sum += __shfl_xor(sum, 16);
    sum += __shfl_xor(sum, 32);
    lrun += sum;

    // P -> bf16 A-frags (m=l15 -> q, k = quad*4+e), in-register
    s4 pa[4];
#pragma unroll
    for (int j = 0; j < 4; j++) pa[j] = cvt4(sacc[j]);

    // retire Vload(s) (+stage(s+1)); keep stage(s+2) in flight
    if (s + 2 < steps) asm volatile("s_waitcnt vmcnt(2)" ::: "memory");
    else               asm volatile("s_waitcnt vmcnt(0)" ::: "memory");
    __builtin_amdgcn_sched_barrier(0);    // MFMA must not hoist above the wait

    // PV from registers only: acc_o[n] += P[q][k] * V^T[d][k]
    __builtin_amdgcn_s_setprio(1);
#pragma unroll
    for (int j = 0; j < 4; j++)
#pragma unroll
      for (int n = 0; n < 4; n++)
        acc_o[n] = mfma16(pa[j], vreg[j][n], acc_o[n]);
    __builtin_amdgcn_s_setprio(0);
  }

  writeout();  // flush q-tile B
}

extern "C" void kernel_launch(void* const* d_in, const int* in_sizes, int n_in,
                              void* d_out, int out_size, void* d_ws, size_t ws_size,
                              hipStream_t stream) {
  const float* x     = (const float*)d_in[0];   // (2,2048,1024) fp32
  const float* w_qkv = (const float*)d_in[1];   // (3072,1024)   fp32
  const float* w_o   = (const float*)d_in[2];   // (1024,1024)   fp32
  float* out  = (float*)d_out;                  // fp32 (4096,1024)
  float* outk = out + (size_t)4194304;
  float* outv = out + (size_t)8388608;

  u16* qkv = (u16*)d_ws;                        // 4096*3072
  u16* vt  = qkv + (size_t)4096 * 3072;         // 32*64*2048
  u16* ao  = vt  + (size_t)4194304;             // 4096*1024
  u16* xb  = ao  + (size_t)4194304;             // 4096*1024
  u16* wqb = xb  + (size_t)4194304;             // 3072*1024
  u16* wob = wqb + (size_t)3145728;             // 1024*1024

  // 0. fused fp32 -> bf16 conversion (xb, wqb, wob contiguous)
  cvt_all<<<4096, 256, 0, stream>>>(x, w_qkv, w_o, xb);

  // 1. qkv(bf16 ws) = xb @ wqb^T; k -> qkv+outk; v -> outv + vt (fused transpose)
  gemm_bt<false, true, 4><<<dim3(24, 32), 256, 0, stream>>>(
      xb, wqb, qkv, outk, outv, vt, 4096, 3072, 1024);
  // 2. flash attention -> ao (bf16 ws): K via LDS pipe, V via register gathers
  attn<<<dim3(16, 32), 256, 0, stream>>>(qkv, vt, ao);
  // 3. out(fp32) = ao @ wob^T: 8 waves on 128x128 tile
  gemm_bt<true, false, 8><<<dim3(8, 32), 512, 0, stream>>>(
      ao, wob, out, nullptr, nullptr, nullptr, 4096, 1024, 1024);
}

// Round 7
// 218.868 us; speedup vs baseline: 1.2779x; 1.2779x over previous
//
#include <hip/hip_runtime.h>
#include <cstdint>

typedef unsigned short u16;
typedef __bf16 bf16x8 __attribute__((ext_vector_type(8)));
typedef float f32x4 __attribute__((ext_vector_type(4)));
typedef short s4 __attribute__((ext_vector_type(4)));

#define T_SEQ 2048
#define NH 16

// RTNE float -> bf16 bits
__device__ __forceinline__ u16 f2bf(float f) {
  union { float f; uint32_t u; } x; x.f = f;
  uint32_t r = (x.u + 0x7fffu + ((x.u >> 16) & 1u)) >> 16;
  return (u16)r;
}

// pack two floats -> two bf16 (RTNE)
__device__ __forceinline__ uint32_t pk2bf(float a, float b) {
  union { float f; uint32_t u; } x, y; x.f = a; y.f = b;
  uint32_t lo = (x.u + 0x7fffu + ((x.u >> 16) & 1u)) >> 16;
  uint32_t hi = (y.u + 0x7fffu + ((y.u >> 16) & 1u)) >> 16;
  return lo | (hi << 16);
}

// 8 fp32 -> 8 bf16 (one uint4 store)
__device__ __forceinline__ void cvt8(u16* dst, const float* src) {
  float4 a = *(const float4*)src;
  float4 b = *(const float4*)(src + 4);
  uint4 o;
  o.x = pk2bf(a.x, a.y); o.y = pk2bf(a.z, a.w);
  o.z = pk2bf(b.x, b.y); o.w = pk2bf(b.z, b.w);
  *(uint4*)dst = o;
}

// fused fp32 -> bf16 conversion of x, w_qkv, w_o (dst regions contiguous in ws)
__global__ __launch_bounds__(256) void cvt_all(const float* __restrict__ x,
                                               const float* __restrict__ wq,
                                               const float* __restrict__ wo,
                                               u16* __restrict__ dst) {
  int i = blockIdx.x * 256 + threadIdx.x;
  const float* src; int off;
  if (i < 524288)      { src = x;  off = 0; }
  else if (i < 917504) { src = wq; off = 524288; }
  else                 { src = wo; off = 917504; }
  cvt8(&dst[(size_t)i * 8], &src[(size_t)(i - off) * 8]);
}

// f32x4 accumulator quad -> 4 bf16
__device__ __forceinline__ s4 cvt4(f32x4 v) {
  union { __bf16 b[4]; s4 s; } u;
  u.b[0] = (__bf16)v[0]; u.b[1] = (__bf16)v[1];
  u.b[2] = (__bf16)v[2]; u.b[3] = (__bf16)v[3];
  return u.s;
}

__device__ __forceinline__ f32x4 mfma16(s4 a, s4 b, f32x4 c) {
#if __has_builtin(__builtin_amdgcn_mfma_f32_16x16x16bf16_1k)
  return __builtin_amdgcn_mfma_f32_16x16x16bf16_1k(a, b, c, 0, 0, 0);
#else
  asm("v_mfma_f32_16x16x16_bf16 %0, %1, %2, %0" : "+v"(c) : "v"(a), "v"(b));
  return c;
#endif
}

// native 2^x
__device__ __forceinline__ float exp2fast(float x) {
#if __has_builtin(__builtin_amdgcn_exp2f)
  return __builtin_amdgcn_exp2f(x);
#else
  float r; asm("v_exp_f32 %0, %1" : "=v"(r) : "v"(x)); return r;
#endif
}

// async 16B global -> LDS (HW scatters lane i at ldsbase + i*16)
__device__ __forceinline__ void gl_lds(const u16* g, u16* ldsbase) {
  __builtin_amdgcn_global_load_lds(
      (const __attribute__((address_space(1))) void*)g,
      (__attribute__((address_space(3))) void*)ldsbase, 16, 0, 0);
}

// C[M,N] = A[M,K] * W[N,K]^T. A,W bf16; C fp32 (CF32) or bf16 ws.
// KV: k cols (1024..2047) -> qkv bf16 + outk fp32; v cols (>=2048) ->
//     outv fp32 + TRANSPOSED bf16 into vt (fused transpose_v).
// tile 128x128, BK=64, global_load_lds staging, XOR-swizzled linear LDS,
// bijective XCD-aware block swizzle (grid %8 == 0).
template <bool CF32, bool KV, int WAVES>
__global__ __launch_bounds__(WAVES * 64) void gemm_bt(
    const u16* __restrict__ A, const u16* __restrict__ W,
    void* __restrict__ Cp, float* __restrict__ outk, float* __restrict__ outv,
    u16* __restrict__ vtp, int M, int N, int K) {
  constexpr int NJ = (WAVES == 4) ? 4 : 2;   // N-frags per wave
  constexpr int SI = 16 / WAVES;             // staging iters (8-row groups)
  __shared__ __align__(16) u16 As[128 * 64];
  __shared__ __align__(16) u16 Bs[128 * 64];
  const int tid  = threadIdx.x;
  const int bid  = blockIdx.y * gridDim.x + blockIdx.x;
  const int per  = (gridDim.x * gridDim.y) >> 3;
  const int swz  = (bid & 7) * per + (bid >> 3);
  const int n0   = (swz % gridDim.x) * 128;
  const int m0   = (swz / gridDim.x) * 128;
  const int tid_ = tid;
  const int lane = tid_ & 63;
  const int wave = tid_ >> 6;
  const int wm   = (WAVES == 4 ? (wave >> 1) : (wave >> 2)) * 64;
  const int wn   = (WAVES == 4 ? (wave & 1) * 64 : (wave & 3) * 32);
  const int l15  = lane & 15;
  const int quad = lane >> 4;
  const int srow = lane >> 3;   // row within 8-row stage group
  const int sc   = lane & 7;    // 16B chunk within row

  f32x4 acc[4][NJ];
#pragma unroll
  for (int i = 0; i < 4; i++)
#pragma unroll
    for (int j = 0; j < NJ; j++) acc[i][j] = (f32x4){0.f, 0.f, 0.f, 0.f};

  for (int k0 = 0; k0 < K; k0 += 64) {
    __syncthreads();
#pragma unroll
    for (int i = 0; i < SI; i++) {
      int r0  = (i * WAVES + wave) * 8;
      int row = r0 + srow;
      int gc  = (sc ^ (row & 7)) << 3;  // pre-swizzled source column (u16)
      gl_lds(&A[(size_t)(m0 + row) * K + k0 + gc], &As[r0 * 64]);
      gl_lds(&W[(size_t)(n0 + row) * K + k0 + gc], &Bs[r0 * 64]);
    }
    __syncthreads();
#pragma unroll
    for (int kk = 0; kk < 64; kk += 32) {
      bf16x8 af[4], bfr[NJ];
#pragma unroll
      for (int i = 0; i < 4; i++) {
        int arow = wm + i * 16 + l15;
        af[i] = *(const bf16x8*)((const char*)As + arow * 128 +
                                 ((((kk >> 3) + quad) ^ (arow & 7)) << 4));
      }
#pragma unroll
      for (int j = 0; j < NJ; j++) {
        int brow = wn + j * 16 + l15;
        bfr[j] = *(const bf16x8*)((const char*)Bs + brow * 128 +
                                  ((((kk >> 3) + quad) ^ (brow & 7)) << 4));
      }
#pragma unroll
      for (int i = 0; i < 4; i++)
#pragma unroll
        for (int j = 0; j < NJ; j++)
          acc[i][j] = __builtin_amdgcn_mfma_f32_16x16x32_bf16(af[i], bfr[j], acc[i][j], 0, 0, 0);
    }
  }
#pragma unroll
  for (int i = 0; i < 4; i++)
#pragma unroll
    for (int j = 0; j < NJ; j++) {
      const int row0 = m0 + wm + i * 16 + quad * 4;  // 4 consecutive rows
      const int col  = n0 + wn + j * 16 + l15;
      if constexpr (CF32) {
#pragma unroll
        for (int r = 0; r < 4; r++)
          ((float*)Cp)[(size_t)(row0 + r) * N + col] = acc[i][j][r];
      } else if (KV && col >= 2048) {
        // v: fp32 output + transposed bf16 into vt (4 consecutive t -> 8B)
        const int hd = col - 2048;
        const int b_ = row0 >> 11, t_ = row0 & 2047;
        uint2 pk;
        pk.x = pk2bf(acc[i][j][0], acc[i][j][1]);
        pk.y = pk2bf(acc[i][j][2], acc[i][j][3]);
        *(uint2*)&vtp[((size_t)(b_ * NH + (hd >> 6)) * 64 + (hd & 63)) * 2048 + t_] = pk;
#pragma unroll
        for (int r = 0; r < 4; r++)
          outv[(size_t)(row0 + r) * 1024 + hd] = acc[i][j][r];
      } else {
#pragma unroll
        for (int r = 0; r < 4; r++) {
          float v = acc[i][j][r];
          ((u16*)Cp)[(size_t)(row0 + r) * N + col] = f2bf(v);
          if constexpr (KV) {
            if (col >= 1024) outk[(size_t)(row0 + r) * 1024 + (col - 1024)] = v;
          }
        }
      }
    }
}

// Flash-style causal attention, swapped QK^T (S^T = mfma(K,Q)).
// Block = 4 waves covering the ADJACENT tile pair (2p, 2p+1): waves 0-1 ->
// tile 2p+1, waves 2-3 -> tile 2p, each wave owning TWO 16-row quadrants
// (rows (wave&1)*32 + {0,16}).  Both tiles consume the same k-tile sequence,
// so ONE staged K/V stream feeds the block, and every K-frag / V-frag
// ds_read feeds 2 MFMAs -> DS-pipe work per tile-compute halves (round-4
// diagnosis: DS pipe ~95% busy was the attn limiter).
// 3-buffer pipeline, counted vmcnt (stage s+2 in flight across barriers).
// p = b ? x : 15-x makes co-resident blocks complementary (uniform CU load).
__global__ __launch_bounds__(256) void attn(const u16* __restrict__ qkv,
                                            const u16* __restrict__ vt,
                                            u16* __restrict__ o) {
  __shared__ __align__(16) u16 Ks[3][64 * 64];
  __shared__ __align__(16) u16 Vts[3][64 * 64];

  const int tid  = threadIdx.x;
  const int bh   = blockIdx.y;
  const int b    = bh >> 4, h = bh & 15;
  const int p    = b ? (int)blockIdx.x : 15 - (int)blockIdx.x;
  const int lane = tid & 63, wave = tid >> 6;
  const int grp  = wave >> 1;           // 0: tile 2p+1, 1: tile 2p
  const int half = wave & 1;            // 32-row half within the tile
  const int l15  = lane & 15, quad = lane >> 4;
  const int srow = lane >> 3, sc = lane & 7;
  const size_t qbase = (size_t)b * T_SEQ * 3072;
  const size_t vbase = (size_t)(b * NH + h) * 64 * 2048;
  const float C = 0.1803368801f;        // 0.125 * log2(e)

  const int qt    = 2 * p + 1 - grp;
  const int steps = 2 * p + 2;

  int wq0[2];
  wq0[0] = qt * 64 + half * 32;
  wq0[1] = wq0[0] + 16;

  // Q fragments for both quadrants (B-operand: n=l15 -> q row), from global
  bf16x8 qf[2][2];
#pragma unroll
  for (int q = 0; q < 2; q++) {
    const u16* qp = &qkv[qbase + (size_t)(wq0[q] + l15) * 3072 + h * 64];
    qf[q][0] = *(const bf16x8*)&qp[quad * 8];
    qf[q][1] = *(const bf16x8*)&qp[32 + quad * 8];
  }

  f32x4 acc_o[2][4];
#pragma unroll
  for (int q = 0; q < 2; q++)
#pragma unroll
    for (int n = 0; n < 4; n++) acc_o[q][n] = (f32x4){0.f, 0.f, 0.f, 0.f};
  float m2run[2] = {-1e30f, -1e30f}, lrun[2] = {0.f, 0.f};

  // async stage of k-tile kt into buffer buf: 4 gl_lds per wave
  auto stage = [&](int buf, int kt) {
    const int k0 = kt * 64;
#pragma unroll
    for (int i = 0; i < 2; i++) {
      int r0  = (wave * 2 + i) * 8;
      int row = r0 + srow;
      int gc  = (sc ^ (row & 7)) << 3;
      gl_lds(&qkv[qbase + (size_t)(k0 + row) * 3072 + 1024 + h * 64 + gc], &Ks[buf][r0 * 64]);
      gl_lds(&vt[vbase + (size_t)row * 2048 + k0 + gc], &Vts[buf][r0 * 64]);
    }
  };

  stage(0, 0);
  stage(1, 1);

  for (int s = 0; s < steps; s++) {
    // retire Q-loads + stage(s); keep stage(s+1) (4 loads) in flight
    if (s < steps - 1) asm volatile("s_waitcnt vmcnt(4)" ::: "memory");
    else               asm volatile("s_waitcnt vmcnt(0)" ::: "memory");
    __builtin_amdgcn_s_barrier();         // Ks/Vts[s%3] landed in all waves
    __builtin_amdgcn_sched_barrier(0);

    if (s + 2 < steps) stage((s + 2) % 3, s + 2);  // overwrites buf[(s-1)%3]

    if (s <= qt) {          // tile 2p (grp=1) skips only the final step
      const int cur = s % 3;
      const int k0  = s * 64;

      // S^T[q][j]: row (quad*4+r) = k_local, col l15 = q-row
      f32x4 sacc[2][4];
#pragma unroll
      for (int q = 0; q < 2; q++)
#pragma unroll
        for (int j = 0; j < 4; j++) sacc[q][j] = (f32x4){0.f, 0.f, 0.f, 0.f};

      __builtin_amdgcn_s_setprio(1);
#pragma unroll
      for (int j = 0; j < 4; j++) {
        int krow = j * 16 + l15;
        const char* kb = (const char*)&Ks[cur][0] + krow * 128;
        bf16x8 kfa = *(const bf16x8*)(kb + ((quad ^ (krow & 7)) << 4));
        bf16x8 kfb = *(const bf16x8*)(kb + (((4 + quad) ^ (krow & 7)) << 4));
#pragma unroll
        for (int q = 0; q < 2; q++) {
          sacc[q][j] = __builtin_amdgcn_mfma_f32_16x16x32_bf16(kfa, qf[q][0], sacc[q][j], 0, 0, 0);
          sacc[q][j] = __builtin_amdgcn_mfma_f32_16x16x32_bf16(kfb, qf[q][1], sacc[q][j], 0, 0, 0);
        }
      }
      __builtin_amdgcn_s_setprio(0);

      if (s == qt) {  // diagonal tile: causal mask on raw scores
#pragma unroll
        for (int q = 0; q < 2; q++)
#pragma unroll
          for (int j = 0; j < 4; j++)
#pragma unroll
            for (int r = 0; r < 4; r++) {
              int k = k0 + j * 16 + quad * 4 + r;
              if (k > wq0[q] + l15) sacc[q][j][r] = -1e30f;
            }
      }

      s4 pa[2][4];
#pragma unroll
      for (int q = 0; q < 2; q++) {
        // row max, tree-shaped
        float mj[4];
#pragma unroll
        for (int j = 0; j < 4; j++)
          mj[j] = fmaxf(fmaxf(sacc[q][j][0], sacc[q][j][1]),
                        fmaxf(sacc[q][j][2], sacc[q][j][3]));
        float mx = fmaxf(fmaxf(mj[0], mj[1]), fmaxf(mj[2], mj[3]));
        mx = fmaxf(mx, __shfl_xor(mx, 16));
        mx = fmaxf(mx, __shfl_xor(mx, 32));
        const float m2x = mx * C;

        // defer-max: only rescale when the max grew by > 8 (log2 domain)
        if (!__all(m2x <= m2run[q] + 8.0f)) {
          const float m2new = fmaxf(m2run[q], m2x);
          const float alpha = exp2fast(m2run[q] - m2new);
          lrun[q] *= alpha;
          m2run[q] = m2new;
#pragma unroll
          for (int r = 0; r < 4; r++) {
            float ar = __shfl(alpha, quad * 4 + r);
#pragma unroll
            for (int n = 0; n < 4; n++) acc_o[q][n][r] *= ar;
          }
        }

        // pexp = exp2(s*C - m2run); tree sum
        const float nm = m2run[q];
        float ts[4];
#pragma unroll
        for (int j = 0; j < 4; j++) {
#pragma unroll
          for (int r = 0; r < 4; r++)
            sacc[q][j][r] = exp2fast(fmaf(sacc[q][j][r], C, -nm));
          ts[j] = (sacc[q][j][0] + sacc[q][j][1]) + (sacc[q][j][2] + sacc[q][j][3]);
        }
        float sum = (ts[0] + ts[1]) + (ts[2] + ts[3]);
        sum += __shfl_xor(sum, 16);
        sum += __shfl_xor(sum, 32);
        lrun[q] += sum;

        // P -> bf16 A-frags (m=l15 -> q-row, k = quad*4+e), in-register
#pragma unroll
        for (int j = 0; j < 4; j++) pa[q][j] = cvt4(sacc[q][j]);
      }

      // PV: each V-frag ds_read feeds BOTH quadrants' mfma16
      __builtin_amdgcn_s_setprio(1);
#pragma unroll
      for (int j = 0; j < 4; j++)
#pragma unroll
        for (int n = 0; n < 4; n++) {
          int vrow = n * 16 + l15;
          int ch = (j * 2 + (quad >> 1)) ^ (vrow & 7);
          const s4 vf = *(const s4*)((const char*)&Vts[cur][0] + vrow * 128 +
                                     (ch << 4) + ((quad & 1) << 3));
#pragma unroll
          for (int q = 0; q < 2; q++)
            acc_o[q][n] = mfma16(pa[q][j], vf, acc_o[q][n]);
        }
      __builtin_amdgcn_s_setprio(0);
    }
  }

  // writeout both quadrants
#pragma unroll
  for (int q = 0; q < 2; q++) {
    const float linv = 1.0f / lrun[q];
#pragma unroll
    for (int r = 0; r < 4; r++) {
      const float lr = __shfl(linv, quad * 4 + r);
      const int row = wq0[q] + quad * 4 + r;
#pragma unroll
      for (int n = 0; n < 4; n++)
        o[(size_t)(b * T_SEQ + row) * 1024 + h * 64 + n * 16 + l15] =
            f2bf(acc_o[q][n][r] * lr);
    }
  }
}

extern "C" void kernel_launch(void* const* d_in, const int* in_sizes, int n_in,
                              void* d_out, int out_size, void* d_ws, size_t ws_size,
                              hipStream_t stream) {
  const float* x     = (const float*)d_in[0];   // (2,2048,1024) fp32
  const float* w_qkv = (const float*)d_in[1];   // (3072,1024)   fp32
  const float* w_o   = (const float*)d_in[2];   // (1024,1024)   fp32
  float* out  = (float*)d_out;                  // fp32 (4096,1024)
  float* outk = out + (size_t)4194304;
  float* outv = out + (size_t)8388608;

  u16* qkv = (u16*)d_ws;                        // 4096*3072
  u16* vt  = qkv + (size_t)4096 * 3072;         // 32*64*2048
  u16* ao  = vt  + (size_t)4194304;             // 4096*1024
  u16* xb  = ao  + (size_t)4194304;             // 4096*1024
  u16* wqb = xb  + (size_t)4194304;             // 3072*1024
  u16* wob = wqb + (size_t)3145728;             // 1024*1024

  // 0. fused fp32 -> bf16 conversion (xb, wqb, wob contiguous)
  cvt_all<<<4096, 256, 0, stream>>>(x, w_qkv, w_o, xb);

  // 1. qkv(bf16 ws) = xb @ wqb^T; k -> qkv+outk; v -> outv + vt (fused transpose)
  gemm_bt<false, true, 4><<<dim3(24, 32), 256, 0, stream>>>(
      xb, wqb, qkv, outk, outv, vt, 4096, 3072, 1024);
  // 2. flash attention -> ao (bf16 ws): paired tiles share one K/V stream
  attn<<<dim3(16, 32), 256, 0, stream>>>(qkv, vt, ao);
  // 3. out(fp32) = ao @ wob^T: 8 waves on 128x128 tile
  gemm_bt<true, false, 8><<<dim3(8, 32), 512, 0, stream>>>(
      ao, wob, out, nullptr, nullptr, nullptr, 4096, 1024, 1024);
}

// Round 8
// 210.130 us; speedup vs baseline: 1.3311x; 1.0416x over previous
//
#include <hip/hip_runtime.h>
#include <cstdint>

typedef unsigned short u16;
typedef __bf16 bf16x8 __attribute__((ext_vector_type(8)));
typedef float f32x4 __attribute__((ext_vector_type(4)));
typedef short s4 __attribute__((ext_vector_type(4)));

#define T_SEQ 2048
#define NH 16

// RTNE float -> bf16 bits
__device__ __forceinline__ u16 f2bf(float f) {
  union { float f; uint32_t u; } x; x.f = f;
  uint32_t r = (x.u + 0x7fffu + ((x.u >> 16) & 1u)) >> 16;
  return (u16)r;
}

// pack two floats -> two bf16 (RTNE)
__device__ __forceinline__ uint32_t pk2bf(float a, float b) {
  union { float f; uint32_t u; } x, y; x.f = a; y.f = b;
  uint32_t lo = (x.u + 0x7fffu + ((x.u >> 16) & 1u)) >> 16;
  uint32_t hi = (y.u + 0x7fffu + ((y.u >> 16) & 1u)) >> 16;
  return lo | (hi << 16);
}

// 8 fp32 -> 8 bf16 (one uint4 store)
__device__ __forceinline__ void cvt8(u16* dst, const float* src) {
  float4 a = *(const float4*)src;
  float4 b = *(const float4*)(src + 4);
  uint4 o;
  o.x = pk2bf(a.x, a.y); o.y = pk2bf(a.z, a.w);
  o.z = pk2bf(b.x, b.y); o.w = pk2bf(b.z, b.w);
  *(uint4*)dst = o;
}

// fused fp32 -> bf16 conversion of x, w_qkv, w_o (dst regions contiguous in ws)
__global__ __launch_bounds__(256) void cvt_all(const float* __restrict__ x,
                                               const float* __restrict__ wq,
                                               const float* __restrict__ wo,
                                               u16* __restrict__ dst) {
  int i = blockIdx.x * 256 + threadIdx.x;
  const float* src; int off;
  if (i < 524288)      { src = x;  off = 0; }
  else if (i < 917504) { src = wq; off = 524288; }
  else                 { src = wo; off = 917504; }
  cvt8(&dst[(size_t)i * 8], &src[(size_t)(i - off) * 8]);
}

// f32x4 accumulator quad -> 4 bf16
__device__ __forceinline__ s4 cvt4(f32x4 v) {
  union { __bf16 b[4]; s4 s; } u;
  u.b[0] = (__bf16)v[0]; u.b[1] = (__bf16)v[1];
  u.b[2] = (__bf16)v[2]; u.b[3] = (__bf16)v[3];
  return u.s;
}

__device__ __forceinline__ f32x4 mfma16(s4 a, s4 b, f32x4 c) {
#if __has_builtin(__builtin_amdgcn_mfma_f32_16x16x16bf16_1k)
  return __builtin_amdgcn_mfma_f32_16x16x16bf16_1k(a, b, c, 0, 0, 0);
#else
  asm("v_mfma_f32_16x16x16_bf16 %0, %1, %2, %0" : "+v"(c) : "v"(a), "v"(b));
  return c;
#endif
}

// native 2^x
__device__ __forceinline__ float exp2fast(float x) {
#if __has_builtin(__builtin_amdgcn_exp2f)
  return __builtin_amdgcn_exp2f(x);
#else
  float r; asm("v_exp_f32 %0, %1" : "=v"(r) : "v"(x)); return r;
#endif
}

// async 16B global -> LDS (HW scatters lane i at ldsbase + i*16)
__device__ __forceinline__ void gl_lds(const u16* g, u16* ldsbase) {
  __builtin_amdgcn_global_load_lds(
      (const __attribute__((address_space(1))) void*)g,
      (__attribute__((address_space(3))) void*)ldsbase, 16, 0, 0);
}

// C[M,N] = A[M,K] * W[N,K]^T. A,W bf16; C fp32 (CF32) or bf16 ws.
// KV: k cols (1024..2047) -> qkv bf16 + outk fp32; v cols (>=2048) ->
//     outv fp32 + TRANSPOSED bf16 into vt (fused transpose_v).
// tile 128x128, BK=64, global_load_lds staging, XOR-swizzled linear LDS,
// bijective XCD-aware block swizzle (grid %8 == 0).
// T3-minimum 2-phase dbuf: stage(t+1) issued BEFORE compute(t), drained after
// -- stage latency hides under the 32-MFMA compute phase.
template <bool CF32, bool KV, int WAVES>
__global__ __launch_bounds__(WAVES * 64) void gemm_bt(
    const u16* __restrict__ A, const u16* __restrict__ W,
    void* __restrict__ Cp, float* __restrict__ outk, float* __restrict__ outv,
    u16* __restrict__ vtp, int M, int N, int K) {
  constexpr int NJ = (WAVES == 4) ? 4 : 2;   // N-frags per wave
  constexpr int SI = 16 / WAVES;             // staging iters (8-row groups)
  __shared__ __align__(16) u16 As[2][128 * 64];
  __shared__ __align__(16) u16 Bs[2][128 * 64];
  const int tid  = threadIdx.x;
  const int bid  = blockIdx.y * gridDim.x + blockIdx.x;
  const int per  = (gridDim.x * gridDim.y) >> 3;
  const int swz  = (bid & 7) * per + (bid >> 3);
  const int n0   = (swz % gridDim.x) * 128;
  const int m0   = (swz / gridDim.x) * 128;
  const int lane = tid & 63;
  const int wave = tid >> 6;
  const int wm   = (WAVES == 4 ? (wave >> 1) : (wave >> 2)) * 64;
  const int wn   = (WAVES == 4 ? (wave & 1) * 64 : (wave & 3) * 32);
  const int l15  = lane & 15;
  const int quad = lane >> 4;
  const int srow = lane >> 3;   // row within 8-row stage group
  const int sc   = lane & 7;    // 16B chunk within row

  f32x4 acc[4][NJ];
#pragma unroll
  for (int i = 0; i < 4; i++)
#pragma unroll
    for (int j = 0; j < NJ; j++) acc[i][j] = (f32x4){0.f, 0.f, 0.f, 0.f};

  auto stage = [&](int d, int k0) {
#pragma unroll
    for (int i = 0; i < SI; i++) {
      int r0  = (i * WAVES + wave) * 8;
      int row = r0 + srow;
      int gc  = (sc ^ (row & 7)) << 3;  // pre-swizzled source column (u16)
      gl_lds(&A[(size_t)(m0 + row) * K + k0 + gc], &As[d][r0 * 64]);
      gl_lds(&W[(size_t)(n0 + row) * K + k0 + gc], &Bs[d][r0 * 64]);
    }
  };

  stage(0, 0);
  asm volatile("s_waitcnt vmcnt(0)" ::: "memory");
  __builtin_amdgcn_s_barrier();
  __builtin_amdgcn_sched_barrier(0);

  const int NT = K >> 6;
  int cur = 0;
  for (int t = 0; t < NT; t++) {
    if (t + 1 < NT) stage(cur ^ 1, (t + 1) * 64);  // in flight under compute
#pragma unroll
    for (int kk = 0; kk < 64; kk += 32) {
      bf16x8 af[4], bfr[NJ];
#pragma unroll
      for (int i = 0; i < 4; i++) {
        int arow = wm + i * 16 + l15;
        af[i] = *(const bf16x8*)((const char*)&As[cur][0] + arow * 128 +
                                 ((((kk >> 3) + quad) ^ (arow & 7)) << 4));
      }
#pragma unroll
      for (int j = 0; j < NJ; j++) {
        int brow = wn + j * 16 + l15;
        bfr[j] = *(const bf16x8*)((const char*)&Bs[cur][0] + brow * 128 +
                                  ((((kk >> 3) + quad) ^ (brow & 7)) << 4));
      }
#pragma unroll
      for (int i = 0; i < 4; i++)
#pragma unroll
        for (int j = 0; j < NJ; j++)
          acc[i][j] = __builtin_amdgcn_mfma_f32_16x16x32_bf16(af[i], bfr[j], acc[i][j], 0, 0, 0);
    }
    asm volatile("s_waitcnt vmcnt(0)" ::: "memory");
    __builtin_amdgcn_s_barrier();
    __builtin_amdgcn_sched_barrier(0);
    cur ^= 1;
  }
#pragma unroll
  for (int i = 0; i < 4; i++)
#pragma unroll
    for (int j = 0; j < NJ; j++) {
      const int row0 = m0 + wm + i * 16 + quad * 4;  // 4 consecutive rows
      const int col  = n0 + wn + j * 16 + l15;
      if constexpr (CF32) {
#pragma unroll
        for (int r = 0; r < 4; r++)
          ((float*)Cp)[(size_t)(row0 + r) * N + col] = acc[i][j][r];
      } else if (KV && col >= 2048) {
        // v: fp32 output + transposed bf16 into vt (4 consecutive t -> 8B)
        const int hd = col - 2048;
        const int b_ = row0 >> 11, t_ = row0 & 2047;
        uint2 pk;
        pk.x = pk2bf(acc[i][j][0], acc[i][j][1]);
        pk.y = pk2bf(acc[i][j][2], acc[i][j][3]);
        *(uint2*)&vtp[((size_t)(b_ * NH + (hd >> 6)) * 64 + (hd & 63)) * 2048 + t_] = pk;
#pragma unroll
        for (int r = 0; r < 4; r++)
          outv[(size_t)(row0 + r) * 1024 + hd] = acc[i][j][r];
      } else {
#pragma unroll
        for (int r = 0; r < 4; r++) {
          float v = acc[i][j][r];
          ((u16*)Cp)[(size_t)(row0 + r) * N + col] = f2bf(v);
          if constexpr (KV) {
            if (col >= 1024) outk[(size_t)(row0 + r) * 1024 + (col - 1024)] = v;
          }
        }
      }
    }
}

// Flash-style causal attention, swapped QK^T (S^T = mfma(K,Q)).
// Block = 4 waves covering the COMPLEMENTARY tile pair (pair, 31-pair):
// each wave owns quadrant `wave` of BOTH tiles.  Tile A's k-range (0..pair)
// is a prefix of tile B's (0..31-pair), so ONE staged K/V stream of
// steps = 32-pair serves both; during the first pair+1 steps every K/V
// fragment read feeds both tiles' MFMAs (DS amortization) while per-wave
// compute stays UNIFORM at 33 units (round-7's imbalance fixed).
// 3-buffer pipeline, counted vmcnt (stage s+2 in flight across barriers).
// pair = b ? x : 15-x spreads long/short-step blocks across CUs.
__global__ __launch_bounds__(256) void attn(const u16* __restrict__ qkv,
                                            const u16* __restrict__ vt,
                                            u16* __restrict__ o) {
  __shared__ __align__(16) u16 Ks[3][64 * 64];
  __shared__ __align__(16) u16 Vts[3][64 * 64];

  const int tid  = threadIdx.x;
  const int bh   = blockIdx.y;
  const int b    = bh >> 4, h = bh & 15;
  const int pair = b ? (int)blockIdx.x : 15 - (int)blockIdx.x;
  const int lane = tid & 63, wave = tid >> 6;
  const int l15  = lane & 15, quad = lane >> 4;
  const int srow = lane >> 3, sc = lane & 7;
  const size_t qbase = (size_t)b * T_SEQ * 3072;
  const size_t vbase = (size_t)(b * NH + h) * 64 * 2048;
  const float C = 0.1803368801f;        // 0.125 * log2(e)

  const int qt[2] = {pair, 31 - pair};  // tile A (prefix), tile B (full)
  const int steps = 32 - pair;

  int wq0[2];
  wq0[0] = qt[0] * 64 + wave * 16;
  wq0[1] = qt[1] * 64 + wave * 16;

  // Q fragments for both tiles' quadrants (B-operand: n=l15 -> q row)
  bf16x8 qf[2][2];
#pragma unroll
  for (int q = 0; q < 2; q++) {
    const u16* qp = &qkv[qbase + (size_t)(wq0[q] + l15) * 3072 + h * 64];
    qf[q][0] = *(const bf16x8*)&qp[quad * 8];
    qf[q][1] = *(const bf16x8*)&qp[32 + quad * 8];
  }

  f32x4 acc_o[2][4];
#pragma unroll
  for (int q = 0; q < 2; q++)
#pragma unroll
    for (int n = 0; n < 4; n++) acc_o[q][n] = (f32x4){0.f, 0.f, 0.f, 0.f};
  float m2run[2] = {-1e30f, -1e30f}, lrun[2] = {0.f, 0.f};

  // async stage of k-tile kt into buffer buf: 4 gl_lds per wave
  auto stage = [&](int buf, int kt) {
    const int k0 = kt * 64;
#pragma unroll
    for (int i = 0; i < 2; i++) {
      int r0  = (wave * 2 + i) * 8;
      int row = r0 + srow;
      int gc  = (sc ^ (row & 7)) << 3;
      gl_lds(&qkv[qbase + (size_t)(k0 + row) * 3072 + 1024 + h * 64 + gc], &Ks[buf][r0 * 64]);
      gl_lds(&vt[vbase + (size_t)row * 2048 + k0 + gc], &Vts[buf][r0 * 64]);
    }
  };

  stage(0, 0);
  stage(1, 1);

  for (int s = 0; s < steps; s++) {
    // retire Q-loads + stage(s); keep stage(s+1) (4 loads) in flight
    if (s < steps - 1) asm volatile("s_waitcnt vmcnt(4)" ::: "memory");
    else               asm volatile("s_waitcnt vmcnt(0)" ::: "memory");
    __builtin_amdgcn_s_barrier();         // Ks/Vts[s%3] landed in all waves
    __builtin_amdgcn_sched_barrier(0);

    if (s + 2 < steps) stage((s + 2) % 3, s + 2);  // overwrites buf[(s-1)%3]

    const bool aAct = (s <= qt[0]);       // tile A active (block-uniform)
    const int cur = s % 3;
    const int k0  = s * 64;

    // K-frags once per j -> feed both tiles' QK^T
    bf16x8 kfr[4][2];
#pragma unroll
    for (int j = 0; j < 4; j++) {
      int krow = j * 16 + l15;
      const char* kb = (const char*)&Ks[cur][0] + krow * 128;
      kfr[j][0] = *(const bf16x8*)(kb + ((quad ^ (krow & 7)) << 4));
      kfr[j][1] = *(const bf16x8*)(kb + (((4 + quad) ^ (krow & 7)) << 4));
    }

    f32x4 sacc[2][4];
    __builtin_amdgcn_s_setprio(1);
#pragma unroll
    for (int j = 0; j < 4; j++) {
      sacc[1][j] = (f32x4){0.f, 0.f, 0.f, 0.f};
      sacc[1][j] = __builtin_amdgcn_mfma_f32_16x16x32_bf16(kfr[j][0], qf[1][0], sacc[1][j], 0, 0, 0);
      sacc[1][j] = __builtin_amdgcn_mfma_f32_16x16x32_bf16(kfr[j][1], qf[1][1], sacc[1][j], 0, 0, 0);
    }
    if (aAct) {
#pragma unroll
      for (int j = 0; j < 4; j++) {
        sacc[0][j] = (f32x4){0.f, 0.f, 0.f, 0.f};
        sacc[0][j] = __builtin_amdgcn_mfma_f32_16x16x32_bf16(kfr[j][0], qf[0][0], sacc[0][j], 0, 0, 0);
        sacc[0][j] = __builtin_amdgcn_mfma_f32_16x16x32_bf16(kfr[j][1], qf[0][1], sacc[0][j], 0, 0, 0);
      }
    }
    __builtin_amdgcn_s_setprio(0);

    s4 pa[2][4];
#pragma unroll
    for (int j = 0; j < 4; j++) pa[0][j] = (s4){0, 0, 0, 0};

#pragma unroll
    for (int q = 0; q < 2; q++) {
      if (q == 0 && !aAct) continue;      // uniform branch

      if (s == qt[q]) {  // diagonal tile: causal mask on raw scores
#pragma unroll
        for (int j = 0; j < 4; j++)
#pragma unroll
          for (int r = 0; r < 4; r++) {
            int k = k0 + j * 16 + quad * 4 + r;
            if (k > wq0[q] + l15) sacc[q][j][r] = -1e30f;
          }
      }

      // row max, tree-shaped
      float mj[4];
#pragma unroll
      for (int j = 0; j < 4; j++)
        mj[j] = fmaxf(fmaxf(sacc[q][j][0], sacc[q][j][1]),
                      fmaxf(sacc[q][j][2], sacc[q][j][3]));
      float mx = fmaxf(fmaxf(mj[0], mj[1]), fmaxf(mj[2], mj[3]));
      mx = fmaxf(mx, __shfl_xor(mx, 16));
      mx = fmaxf(mx, __shfl_xor(mx, 32));
      const float m2x = mx * C;

      // defer-max: only rescale when the max grew by > 8 (log2 domain)
      if (!__all(m2x <= m2run[q] + 8.0f)) {
        const float m2new = fmaxf(m2run[q], m2x);
        const float alpha = exp2fast(m2run[q] - m2new);
        lrun[q] *= alpha;
        m2run[q] = m2new;
#pragma unroll
        for (int r = 0; r < 4; r++) {
          float ar = __shfl(alpha, quad * 4 + r);
#pragma unroll
          for (int n = 0; n < 4; n++) acc_o[q][n][r] *= ar;
        }
      }

      // pexp = exp2(s*C - m2run); tree sum
      const float nm = m2run[q];
      float ts[4];
#pragma unroll
      for (int j = 0; j < 4; j++) {
#pragma unroll
        for (int r = 0; r < 4; r++)
          sacc[q][j][r] = exp2fast(fmaf(sacc[q][j][r], C, -nm));
        ts[j] = (sacc[q][j][0] + sacc[q][j][1]) + (sacc[q][j][2] + sacc[q][j][3]);
      }
      float sum = (ts[0] + ts[1]) + (ts[2] + ts[3]);
      sum += __shfl_xor(sum, 16);
      sum += __shfl_xor(sum, 32);
      lrun[q] += sum;

      // P -> bf16 A-frags (m=l15 -> q-row, k = quad*4+e), in-register
#pragma unroll
      for (int j = 0; j < 4; j++) pa[q][j] = cvt4(sacc[q][j]);
    }

    // PV: each V-frag ds_read feeds both tiles (pa[0]=0 when A inactive)
    __builtin_amdgcn_s_setprio(1);
#pragma unroll
    for (int j = 0; j < 4; j++)
#pragma unroll
      for (int n = 0; n < 4; n++) {
        int vrow = n * 16 + l15;
        int ch = (j * 2 + (quad >> 1)) ^ (vrow & 7);
        const s4 vf = *(const s4*)((const char*)&Vts[cur][0] + vrow * 128 +
                                   (ch << 4) + ((quad & 1) << 3));
        acc_o[1][n] = mfma16(pa[1][j], vf, acc_o[1][n]);
        acc_o[0][n] = mfma16(pa[0][j], vf, acc_o[0][n]);
      }
    __builtin_amdgcn_s_setprio(0);
  }

  // writeout both tiles' quadrants
#pragma unroll
  for (int q = 0; q < 2; q++) {
    const float linv = 1.0f / lrun[q];
#pragma unroll
    for (int r = 0; r < 4; r++) {
      const float lr = __shfl(linv, quad * 4 + r);
      const int row = wq0[q] + quad * 4 + r;
#pragma unroll
      for (int n = 0; n < 4; n++)
        o[(size_t)(b * T_SEQ + row) * 1024 + h * 64 + n * 16 + l15] =
            f2bf(acc_o[q][n][r] * lr);
    }
  }
}

extern "C" void kernel_launch(void* const* d_in, const int* in_sizes, int n_in,
                              void* d_out, int out_size, void* d_ws, size_t ws_size,
                              hipStream_t stream) {
  const float* x     = (const float*)d_in[0];   // (2,2048,1024) fp32
  const float* w_qkv = (const float*)d_in[1];   // (3072,1024)   fp32
  const float* w_o   = (const float*)d_in[2];   // (1024,1024)   fp32
  float* out  = (float*)d_out;                  // fp32 (4096,1024)
  float* outk = out + (size_t)4194304;
  float* outv = out + (size_t)8388608;

  u16* qkv = (u16*)d_ws;                        // 4096*3072
  u16* vt  = qkv + (size_t)4096 * 3072;         // 32*64*2048
  u16* ao  = vt  + (size_t)4194304;             // 4096*1024
  u16* xb  = ao  + (size_t)4194304;             // 4096*1024
  u16* wqb = xb  + (size_t)4194304;             // 3072*1024
  u16* wob = wqb + (size_t)3145728;             // 1024*1024

  // 0. fused fp32 -> bf16 conversion (xb, wqb, wob contiguous)
  cvt_all<<<4096, 256, 0, stream>>>(x, w_qkv, w_o, xb);

  // 1. qkv(bf16 ws) = xb @ wqb^T; k -> qkv+outk; v -> outv + vt (fused transpose)
  gemm_bt<false, true, 4><<<dim3(24, 32), 256, 0, stream>>>(
      xb, wqb, qkv, outk, outv, vt, 4096, 3072, 1024);
  // 2. flash attention -> ao (bf16 ws): complementary pair shares K/V stream
  attn<<<dim3(16, 32), 256, 0, stream>>>(qkv, vt, ao);
  // 3. out(fp32) = ao @ wob^T: 8 waves on 128x128 tile
  gemm_bt<true, false, 8><<<dim3(8, 32), 512, 0, stream>>>(
      ao, wob, out, nullptr, nullptr, nullptr, 4096, 1024, 1024);
}

// Round 9
// 200.316 us; speedup vs baseline: 1.3963x; 1.0490x over previous
//
#include <hip/hip_runtime.h>
#include <cstdint>

typedef unsigned short u16;
typedef __bf16 bf16x8 __attribute__((ext_vector_type(8)));
typedef float f32x4 __attribute__((ext_vector_type(4)));
typedef short s4 __attribute__((ext_vector_type(4)));

#define T_SEQ 2048
#define NH 16

// RTNE float -> bf16 bits
__device__ __forceinline__ u16 f2bf(float f) {
  union { float f; uint32_t u; } x; x.f = f;
  uint32_t r = (x.u + 0x7fffu + ((x.u >> 16) & 1u)) >> 16;
  return (u16)r;
}

// pack two floats -> two bf16 (RTNE)
__device__ __forceinline__ uint32_t pk2bf(float a, float b) {
  union { float f; uint32_t u; } x, y; x.f = a; y.f = b;
  uint32_t lo = (x.u + 0x7fffu + ((x.u >> 16) & 1u)) >> 16;
  uint32_t hi = (y.u + 0x7fffu + ((y.u >> 16) & 1u)) >> 16;
  return lo | (hi << 16);
}

// 8 fp32 -> 8 bf16 (one uint4 store)
__device__ __forceinline__ void cvt8(u16* dst, const float* src) {
  float4 a = *(const float4*)src;
  float4 b = *(const float4*)(src + 4);
  uint4 o;
  o.x = pk2bf(a.x, a.y); o.y = pk2bf(a.z, a.w);
  o.z = pk2bf(b.x, b.y); o.w = pk2bf(b.z, b.w);
  *(uint4*)dst = o;
}

// fused fp32 -> bf16 conversion of x, w_qkv, w_o (dst regions contiguous in ws)
__global__ __launch_bounds__(256) void cvt_all(const float* __restrict__ x,
                                               const float* __restrict__ wq,
                                               const float* __restrict__ wo,
                                               u16* __restrict__ dst) {
  int i = blockIdx.x * 256 + threadIdx.x;
  const float* src; int off;
  if (i < 524288)      { src = x;  off = 0; }
  else if (i < 917504) { src = wq; off = 524288; }
  else                 { src = wo; off = 917504; }
  cvt8(&dst[(size_t)i * 8], &src[(size_t)(i - off) * 8]);
}

// f32x4 accumulator quad -> 4 bf16
__device__ __forceinline__ s4 cvt4(f32x4 v) {
  union { __bf16 b[4]; s4 s; } u;
  u.b[0] = (__bf16)v[0]; u.b[1] = (__bf16)v[1];
  u.b[2] = (__bf16)v[2]; u.b[3] = (__bf16)v[3];
  return u.s;
}

__device__ __forceinline__ f32x4 mfma16(s4 a, s4 b, f32x4 c) {
#if __has_builtin(__builtin_amdgcn_mfma_f32_16x16x16bf16_1k)
  return __builtin_amdgcn_mfma_f32_16x16x16bf16_1k(a, b, c, 0, 0, 0);
#else
  asm("v_mfma_f32_16x16x16_bf16 %0, %1, %2, %0" : "+v"(c) : "v"(a), "v"(b));
  return c;
#endif
}

// native 2^x
__device__ __forceinline__ float exp2fast(float x) {
#if __has_builtin(__builtin_amdgcn_exp2f)
  return __builtin_amdgcn_exp2f(x);
#else
  float r; asm("v_exp_f32 %0, %1" : "=v"(r) : "v"(x)); return r;
#endif
}

// async 16B global -> LDS (HW scatters lane i at ldsbase + i*16)
__device__ __forceinline__ void gl_lds(const u16* g, u16* ldsbase) {
  __builtin_amdgcn_global_load_lds(
      (const __attribute__((address_space(1))) void*)g,
      (__attribute__((address_space(3))) void*)ldsbase, 16, 0, 0);
}

// C[M,N] = A[M,K] * W[N,K]^T. A,W bf16; C fp32 (CF32) or bf16 ws.
// KV: k cols (1024..2047) -> qkv bf16 + outk fp32; v cols (>=2048) ->
//     outv fp32 + TRANSPOSED bf16 into vt (fused transpose_v).
// tile 128x128, BK=64, global_load_lds staging, XOR-swizzled linear LDS,
// bijective XCD-aware block swizzle (grid %8 == 0).
// T3-minimum 2-phase dbuf: stage(t+1) issued BEFORE compute(t), drained after
// -- stage latency hides under the 32-MFMA compute phase.
template <bool CF32, bool KV, int WAVES>
__global__ __launch_bounds__(WAVES * 64) void gemm_bt(
    const u16* __restrict__ A, const u16* __restrict__ W,
    void* __restrict__ Cp, float* __restrict__ outk, float* __restrict__ outv,
    u16* __restrict__ vtp, int M, int N, int K) {
  constexpr int NJ = (WAVES == 4) ? 4 : 2;   // N-frags per wave
  constexpr int SI = 16 / WAVES;             // staging iters (8-row groups)
  __shared__ __align__(16) u16 As[2][128 * 64];
  __shared__ __align__(16) u16 Bs[2][128 * 64];
  const int tid  = threadIdx.x;
  const int bid  = blockIdx.y * gridDim.x + blockIdx.x;
  const int per  = (gridDim.x * gridDim.y) >> 3;
  const int swz  = (bid & 7) * per + (bid >> 3);
  const int n0   = (swz % gridDim.x) * 128;
  const int m0   = (swz / gridDim.x) * 128;
  const int lane = tid & 63;
  const int wave = tid >> 6;
  const int wm   = (WAVES == 4 ? (wave >> 1) : (wave >> 2)) * 64;
  const int wn   = (WAVES == 4 ? (wave & 1) * 64 : (wave & 3) * 32);
  const int l15  = lane & 15;
  const int quad = lane >> 4;
  const int srow = lane >> 3;   // row within 8-row stage group
  const int sc   = lane & 7;    // 16B chunk within row

  f32x4 acc[4][NJ];
#pragma unroll
  for (int i = 0; i < 4; i++)
#pragma unroll
    for (int j = 0; j < NJ; j++) acc[i][j] = (f32x4){0.f, 0.f, 0.f, 0.f};

  auto stage = [&](int d, int k0) {
#pragma unroll
    for (int i = 0; i < SI; i++) {
      int r0  = (i * WAVES + wave) * 8;
      int row = r0 + srow;
      int gc  = (sc ^ (row & 7)) << 3;  // pre-swizzled source column (u16)
      gl_lds(&A[(size_t)(m0 + row) * K + k0 + gc], &As[d][r0 * 64]);
      gl_lds(&W[(size_t)(n0 + row) * K + k0 + gc], &Bs[d][r0 * 64]);
    }
  };

  stage(0, 0);
  asm volatile("s_waitcnt vmcnt(0)" ::: "memory");
  __builtin_amdgcn_s_barrier();
  __builtin_amdgcn_sched_barrier(0);

  const int NT = K >> 6;
  int cur = 0;
  for (int t = 0; t < NT; t++) {
    if (t + 1 < NT) stage(cur ^ 1, (t + 1) * 64);  // in flight under compute
#pragma unroll
    for (int kk = 0; kk < 64; kk += 32) {
      bf16x8 af[4], bfr[NJ];
#pragma unroll
      for (int i = 0; i < 4; i++) {
        int arow = wm + i * 16 + l15;
        af[i] = *(const bf16x8*)((const char*)&As[cur][0] + arow * 128 +
                                 ((((kk >> 3) + quad) ^ (arow & 7)) << 4));
      }
#pragma unroll
      for (int j = 0; j < NJ; j++) {
        int brow = wn + j * 16 + l15;
        bfr[j] = *(const bf16x8*)((const char*)&Bs[cur][0] + brow * 128 +
                                  ((((kk >> 3) + quad) ^ (brow & 7)) << 4));
      }
#pragma unroll
      for (int i = 0; i < 4; i++)
#pragma unroll
        for (int j = 0; j < NJ; j++)
          acc[i][j] = __builtin_amdgcn_mfma_f32_16x16x32_bf16(af[i], bfr[j], acc[i][j], 0, 0, 0);
    }
    asm volatile("s_waitcnt vmcnt(0)" ::: "memory");
    __builtin_amdgcn_s_barrier();
    __builtin_amdgcn_sched_barrier(0);
    cur ^= 1;
  }
#pragma unroll
  for (int i = 0; i < 4; i++)
#pragma unroll
    for (int j = 0; j < NJ; j++) {
      const int row0 = m0 + wm + i * 16 + quad * 4;  // 4 consecutive rows
      const int col  = n0 + wn + j * 16 + l15;
      if constexpr (CF32) {
#pragma unroll
        for (int r = 0; r < 4; r++)
          ((float*)Cp)[(size_t)(row0 + r) * N + col] = acc[i][j][r];
      } else if (KV && col >= 2048) {
        // v: fp32 output + transposed bf16 into vt (4 consecutive t -> 8B)
        const int hd = col - 2048;
        const int b_ = row0 >> 11, t_ = row0 & 2047;
        uint2 pk;
        pk.x = pk2bf(acc[i][j][0], acc[i][j][1]);
        pk.y = pk2bf(acc[i][j][2], acc[i][j][3]);
        *(uint2*)&vtp[((size_t)(b_ * NH + (hd >> 6)) * 64 + (hd & 63)) * 2048 + t_] = pk;
#pragma unroll
        for (int r = 0; r < 4; r++)
          outv[(size_t)(row0 + r) * 1024 + hd] = acc[i][j][r];
      } else {
#pragma unroll
        for (int r = 0; r < 4; r++) {
          float v = acc[i][j][r];
          ((u16*)Cp)[(size_t)(row0 + r) * N + col] = f2bf(v);
          if constexpr (KV) {
            if (col >= 1024) outk[(size_t)(row0 + r) * 1024 + (col - 1024)] = v;
          }
        }
      }
    }
}

// Flash-style causal attention, swapped QK^T (S^T = mfma(K,Q)).
// ONE 64-row q-tile per block (grid 32x32 = 1024 blocks -> 4 blocks/CU,
// 16 waves/CU: 2x round-8's residency; latency stalls were ~50% of attn).
// 2-buffer K/V LDS pipeline (32 KB/block): per step vmcnt(0) retires the
// stage issued a full compute-phase earlier (L2-resident stream), one
// barrier/step, stage(s+1) issued right after the barrier.
// Load balance: co-scheduled blocks {by, by+8, by+16, by+24} (same bx ->
// same CU under round-robin dispatch) get qt with step counts
// {u+1, 32-u, v+1, 32-v}, v=(u+16)&31 -> EVERY CU-quad sums to 66 steps;
// mapping is bijective in bx for each head.
__global__ __launch_bounds__(256) void attn(const u16* __restrict__ qkv,
                                            const u16* __restrict__ vt,
                                            u16* __restrict__ o) {
  __shared__ __align__(16) u16 Ks[2][64 * 64];
  __shared__ __align__(16) u16 Vts[2][64 * 64];

  const int tid  = threadIdx.x;
  const int bx   = blockIdx.x;          // 0..31
  const int by   = blockIdx.y;          // bh = b*16+h, 0..31
  const int b    = by >> 4, h = by & 15;
  const int lane = tid & 63, wave = tid >> 6;
  const int l15  = lane & 15, quad = lane >> 4;
  const int srow = lane >> 3, sc = lane & 7;
  const size_t qbase = (size_t)b * T_SEQ * 3072;
  const size_t vbase = (size_t)(b * NH + h) * 64 * 2048;
  const float C = 0.1803368801f;        // 0.125 * log2(e)

  // constant-sum balanced, per-head bijective q-tile assignment
  const int u  = (bx + (by & 7) * 5) & 31;
  const int c  = by >> 3;               // 0..3: co-resident quad index
  const int v_ = (u + ((c >> 1) << 4)) & 31;
  const int qt = (c & 1) ? (31 - v_) : v_;
  const int steps = qt + 1;

  const int wq0  = qt * 64 + wave * 16;
  const int qrow = wq0 + l15;

  // Q fragments (B-operand: n=l15 -> q row), loaded once from global
  const u16* qp = &qkv[qbase + (size_t)qrow * 3072 + h * 64];
  const bf16x8 qf0 = *(const bf16x8*)&qp[quad * 8];
  const bf16x8 qf1 = *(const bf16x8*)&qp[32 + quad * 8];

  f32x4 acc_o[4];
#pragma unroll
  for (int n = 0; n < 4; n++) acc_o[n] = (f32x4){0.f, 0.f, 0.f, 0.f};
  float m2run = -1e30f, lrun = 0.f;

  // async stage of k-tile kt into buffer buf: 4 gl_lds per wave (64 rows/block)
  auto stage = [&](int buf, int kt) {
    const int k0 = kt * 64;
#pragma unroll
    for (int i = 0; i < 2; i++) {
      int r0  = (wave * 2 + i) * 8;
      int row = r0 + srow;
      int gc  = (sc ^ (row & 7)) << 3;
      gl_lds(&qkv[qbase + (size_t)(k0 + row) * 3072 + 1024 + h * 64 + gc], &Ks[buf][r0 * 64]);
      gl_lds(&vt[vbase + (size_t)row * 2048 + k0 + gc], &Vts[buf][r0 * 64]);
    }
  };

  stage(0, 0);

  for (int s = 0; s < steps; s++) {
    const int cur = s & 1;
    // stage(s) (4 loads, issued a full step earlier) must land; nothing else
    // is outstanding -> vmcnt(0).  One barrier per step.
    asm volatile("s_waitcnt vmcnt(0)" ::: "memory");
    __builtin_amdgcn_s_barrier();
    __builtin_amdgcn_sched_barrier(0);

    // all waves finished compute(s-1) (read buf cur^1) before this barrier,
    // so overwriting buf cur^1 with stage(s+1) is safe; it has the whole
    // compute(s) phase to land.
    if (s + 1 < steps) stage(cur ^ 1, s + 1);

    const int k0 = s * 64;

    // S^T[j]: row (quad*4+r) = k_local, col l15 = q  (swizzled Ks reads)
    f32x4 sacc[4];
#pragma unroll
    for (int j = 0; j < 4; j++) sacc[j] = (f32x4){0.f, 0.f, 0.f, 0.f};
    __builtin_amdgcn_s_setprio(1);
#pragma unroll
    for (int j = 0; j < 4; j++) {
      int krow = j * 16 + l15;
      const char* kb = (const char*)&Ks[cur][0] + krow * 128;
      bf16x8 kfa = *(const bf16x8*)(kb + ((quad ^ (krow & 7)) << 4));
      bf16x8 kfb = *(const bf16x8*)(kb + (((4 + quad) ^ (krow & 7)) << 4));
      sacc[j] = __builtin_amdgcn_mfma_f32_16x16x32_bf16(kfa, qf0, sacc[j], 0, 0, 0);
      sacc[j] = __builtin_amdgcn_mfma_f32_16x16x32_bf16(kfb, qf1, sacc[j], 0, 0, 0);
    }
    __builtin_amdgcn_s_setprio(0);

    if (s == qt) {  // diagonal tile: causal mask on raw scores
#pragma unroll
      for (int j = 0; j < 4; j++)
#pragma unroll
        for (int r = 0; r < 4; r++) {
          int k = k0 + j * 16 + quad * 4 + r;
          if (k > qrow) sacc[j][r] = -1e30f;
        }
    }

    // row max, tree-shaped
    float mj[4];
#pragma unroll
    for (int j = 0; j < 4; j++)
      mj[j] = fmaxf(fmaxf(sacc[j][0], sacc[j][1]), fmaxf(sacc[j][2], sacc[j][3]));
    float mx = fmaxf(fmaxf(mj[0], mj[1]), fmaxf(mj[2], mj[3]));
    mx = fmaxf(mx, __shfl_xor(mx, 16));
    mx = fmaxf(mx, __shfl_xor(mx, 32));
    const float m2x = mx * C;

    // defer-max: only rescale when the max grew by > 8 (log2 domain)
    if (!__all(m2x <= m2run + 8.0f)) {
      const float m2new = fmaxf(m2run, m2x);
      const float alpha = exp2fast(m2run - m2new);
      lrun *= alpha;
      m2run = m2new;
#pragma unroll
      for (int r = 0; r < 4; r++) {
        float ar = __shfl(alpha, quad * 4 + r);
#pragma unroll
        for (int n = 0; n < 4; n++) acc_o[n][r] *= ar;
      }
    }

    // p = exp2(s*C - m2run); tree sum
    const float nm = m2run;
    float ts[4];
#pragma unroll
    for (int j = 0; j < 4; j++) {
#pragma unroll
      for (int r = 0; r < 4; r++) sacc[j][r] = exp2fast(fmaf(sacc[j][r], C, -nm));
      ts[j] = (sacc[j][0] + sacc[j][1]) + (sacc[j][2] + sacc[j][3]);
    }
    float sum = (ts[0] + ts[1]) + (ts[2] + ts[3]);
    sum += __shfl_xor(sum, 16);
    sum += __shfl_xor(sum, 32);
    lrun += sum;

    // P -> bf16 A-frags (m=l15 -> q, k = quad*4+e), in-register
    s4 pa[4];
#pragma unroll
    for (int j = 0; j < 4; j++) pa[j] = cvt4(sacc[j]);

    // PV: B-frag = V^T[d = n*16+l15][k0 + j*16+quad*4 ..+3], swizzled b64
    __builtin_amdgcn_s_setprio(1);
#pragma unroll
    for (int j = 0; j < 4; j++)
#pragma unroll
      for (int n = 0; n < 4; n++) {
        int vrow = n * 16 + l15;
        int ch = (j * 2 + (quad >> 1)) ^ (vrow & 7);
        const s4 vf = *(const s4*)((const char*)&Vts[cur][0] + vrow * 128 +
                                   (ch << 4) + ((quad & 1) << 3));
        acc_o[n] = mfma16(pa[j], vf, acc_o[n]);
      }
    __builtin_amdgcn_s_setprio(0);
  }

  const float linv = 1.0f / lrun;
#pragma unroll
  for (int r = 0; r < 4; r++) {
    const float lr = __shfl(linv, quad * 4 + r);
    const int row = wq0 + quad * 4 + r;
#pragma unroll
    for (int n = 0; n < 4; n++)
      o[(size_t)(b * T_SEQ + row) * 1024 + h * 64 + n * 16 + l15] =
          f2bf(acc_o[n][r] * lr);
  }
}

extern "C" void kernel_launch(void* const* d_in, const int* in_sizes, int n_in,
                              void* d_out, int out_size, void* d_ws, size_t ws_size,
                              hipStream_t stream) {
  const float* x     = (const float*)d_in[0];   // (2,2048,1024) fp32
  const float* w_qkv = (const float*)d_in[1];   // (3072,1024)   fp32
  const float* w_o   = (const float*)d_in[2];   // (1024,1024)   fp32
  float* out  = (float*)d_out;                  // fp32 (4096,1024)
  float* outk = out + (size_t)4194304;
  float* outv = out + (size_t)8388608;

  u16* qkv = (u16*)d_ws;                        // 4096*3072
  u16* vt  = qkv + (size_t)4096 * 3072;         // 32*64*2048
  u16* ao  = vt  + (size_t)4194304;             // 4096*1024
  u16* xb  = ao  + (size_t)4194304;             // 4096*1024
  u16* wqb = xb  + (size_t)4194304;             // 3072*1024
  u16* wob = wqb + (size_t)3145728;             // 1024*1024

  // 0. fused fp32 -> bf16 conversion (xb, wqb, wob contiguous)
  cvt_all<<<4096, 256, 0, stream>>>(x, w_qkv, w_o, xb);

  // 1. qkv(bf16 ws) = xb @ wqb^T; k -> qkv+outk; v -> outv + vt (fused transpose)
  gemm_bt<false, true, 4><<<dim3(24, 32), 256, 0, stream>>>(
      xb, wqb, qkv, outk, outv, vt, 4096, 3072, 1024);
  // 2. flash attention -> ao (bf16 ws): 1 tile/block, 1024 blocks, 2-buf pipe
  attn<<<dim3(32, 32), 256, 0, stream>>>(qkv, vt, ao);
  // 3. out(fp32) = ao @ wob^T: 8 waves on 128x128 tile
  gemm_bt<true, false, 8><<<dim3(8, 32), 512, 0, stream>>>(
      ao, wob, out, nullptr, nullptr, nullptr, 4096, 1024, 1024);
}